// Round 7
// baseline (404.874 us; speedup 1.0000x reference)
//
#include <hip/hip_runtime.h>

// Problem constants
#define BN 32768
#define KN 5
#define LN 128
#define HN 3
#define ROWS (BN*KN)        // 163840
#define BK ROWS
#define MT 32               // rows per tile
#define TILES (ROWS/MT)     // 5120
#define WGS 512
#define TPW (TILES/WGS)     // 10 tiles per workgroup
#define THREADS 512         // 8 waves
#define ASTR 168            // A row stride bf16: [emb16|h128|zero16] + 8 pad
#define LOG2E 1.44269504089f

using bf16x8 = __attribute__((ext_vector_type(8))) __bf16;
using bf16x2 = __attribute__((ext_vector_type(2))) __bf16;
using f32x4  = __attribute__((ext_vector_type(4))) float;
using u16x8  = __attribute__((ext_vector_type(8))) unsigned short;

__device__ inline unsigned short f2bf(float x) {
    union { float f; unsigned u; } v; v.f = x;
    unsigned r = v.u + 0x7FFFu + ((v.u >> 16) & 1u);   // RNE
    return (unsigned short)(r >> 16);
}
#if __has_builtin(__builtin_amdgcn_cvt_pk_bf16_f32)
__device__ inline unsigned short f2bf_fast(float x) {
    union { bf16x2 v; unsigned short us[2]; } u;
    u.v = __builtin_amdgcn_cvt_pk_bf16_f32(x, x);
    return u.us[0];
}
#else
__device__ inline unsigned short f2bf_fast(float x) { return f2bf(x); }
#endif
__device__ inline float bf2f(unsigned short b) {
    union { unsigned u; float f; } v; v.u = ((unsigned)b) << 16; return v.f;
}
__device__ inline float sigm(float x) {
    return __builtin_amdgcn_rcpf(1.0f + __builtin_amdgcn_exp2f(-LOG2E * x));
}
__device__ inline f32x4 splat4(float x) { f32x4 r; r[0]=x; r[1]=x; r[2]=x; r[3]=x; return r; }

// ---- prepack: stacked [W_ih|W_hh|0] bf16 fragments (gate scales folded) ----
// Layout: uint4 Bpk[(kt*4+t)*512 + wv*64 + lane]; per lane 8 bf16 (16B):
// n = t*128 + wv*16 + (lane&15), k = kt*32 + (lane>>4)*8 + j
__global__ __launch_bounds__(256)
void prepack_kernel(const float* __restrict__ Wih, const float* __restrict__ Whh,
                    uint4* __restrict__ Bpk)
{
    const int gid  = blockIdx.x * 256 + threadIdx.x;   // 0..10239
    const int lane = gid & 63;
    const int w    = gid >> 6;          // 0..159 = kt*32 + t*8 + wv
    const int wv   = w & 7;
    const int t    = (w >> 3) & 3;
    const int kt   = w >> 5;
    const float sc = (t == 2) ? (2.0f * LOG2E) : (-LOG2E);
    const int n  = t * 128 + wv * 16 + (lane & 15);
    const int k0 = kt * 32 + (lane >> 4) * 8;
    union { uint4 u; unsigned short us[8]; } pk;
    #pragma unroll
    for (int j = 0; j < 8; ++j) {
        const int ks = k0 + j;
        float v = 0.0f;
        if (ks < 16)       v = Wih[n * 16 + ks];
        else if (ks < 144) v = Whh[n * 128 + (ks - 16)];
        pk.us[j] = f2bf(sc * v);
    }
    Bpk[gid] = pk.u;
}

__global__ __launch_bounds__(THREADS, 4)   // <=128 total regs -> 4 waves/SIMD, 2 wg/CU
void wahead_kernel(const float* __restrict__ z,   const float* __restrict__ anchors,
                   const float* __restrict__ W1,  const float* __restrict__ b1,
                   const float* __restrict__ W2,  const float* __restrict__ b2,
                   const float* __restrict__ bih, const float* __restrict__ bhh,
                   const float* __restrict__ Wp,  const float* __restrict__ bp,
                   const float* __restrict__ Wr,  const float* __restrict__ br,
                   const uint4* __restrict__ Bpk, float* __restrict__ out)
{
    __shared__ unsigned short sA[2 * MT * ASTR];   // ping-pong [emb|h|0] bf16, 21.5 KB
    __shared__ float sW1[32], sb1[16], sW2[16 * 17], sb2[16], sWp[128], sWr[384];

    const int tid  = threadIdx.x;
    const int wv   = tid >> 6;       // wave 0..7: owns l-cols wv*16..wv*16+15 of each gate
    const int lane = tid & 63;
    const int quad = lane >> 4;
    const int cc   = lane & 15;

    // ---- stage small constant weights into LDS ----
    if (tid < 32)  sW1[tid] = W1[tid];
    if (tid < 16)  { sb1[tid] = b1[tid]; sb2[tid] = b2[tid]; }
    if (tid < 256) sW2[(tid >> 4) * 17 + (tid & 15)] = W2[tid];   // sW2[col*17+hh]
    if (tid < 128) sWp[tid] = Wp[tid];
    if (tid < 384) sWr[tid] = Wr[tid];

    // scaled biases (i,f,o: -log2e; g: +2log2e) — folded like the B weights
    float biasv[4];
    #pragma unroll
    for (int t = 0; t < 4; ++t) {
        const float sc = (t == 2) ? (2.0f * LOG2E) : (-LOG2E);
        const int n = t * 128 + wv * 16 + cc;
        biasv[t] = sc * (bih[n] + bhh[n]);
    }
    const float bpv = bp[0];
    const float br0 = br[0], br1 = br[1], br2 = br[2];

    // per-wave B stream base: Bpk[(kt*4+t)*512 + wv*64 + lane]
    const uint4* Bw = Bpk + wv * 64 + lane;

    __syncthreads();   // consts staged

    const int erow = tid >> 4;   // 0..31 (16 threads per row)
    const int esub = tid & 15;   // 0..15

    #pragma unroll 1
    for (int ti = 0; ti < TPW; ++ti) {
        const int tile = blockIdx.x * TPW + ti;
        const int r0g  = tile * MT;

        // -------- staging: emb MLP (1 col/thread) + zero-pad + z --------
        {
            const int gr = r0g + erow;
            const float ax = anchors[gr * 2], ay = anchors[gr * 2 + 1];
            float acc_e = sb2[esub];
            #pragma unroll
            for (int hh = 0; hh < 16; ++hh) {
                float pre = fmaf(sW1[hh * 2], ax, fmaf(sW1[hh * 2 + 1], ay, sb1[hh]));
                pre = fmaxf(pre, 0.0f);
                acc_e = fmaf(pre, sW2[esub * 17 + hh], acc_e);
            }
            const unsigned short eb = f2bf(acc_e);
            sA[0 * MT * ASTR + erow * ASTR + esub] = eb;        // emb both buffers
            sA[1 * MT * ASTR + erow * ASTR + esub] = eb;
            sA[0 * MT * ASTR + erow * ASTR + 144 + esub] = 0;   // zero k-pad
            sA[1 * MT * ASTR + erow * ASTR + 144 + esub] = 0;
            // initial h = z[b] (bf16) into buffer 0, cols 16..143
            const unsigned b_idx = (unsigned)gr / 5u;
            const float4* zp = reinterpret_cast<const float4*>(z + (size_t)b_idx * 128 + esub * 8);
            const float4 z0 = zp[0], z1 = zp[1];
            union { u16x8 v; unsigned short us[8]; } zz;
            zz.us[0]=f2bf(z0.x); zz.us[1]=f2bf(z0.y); zz.us[2]=f2bf(z0.z); zz.us[3]=f2bf(z0.w);
            zz.us[4]=f2bf(z1.x); zz.us[5]=f2bf(z1.y); zz.us[6]=f2bf(z1.z); zz.us[7]=f2bf(z1.w);
            *reinterpret_cast<u16x8*>(&sA[erow * ASTR + 16 + esub * 8]) = zz.v;
        }

        float cst[8];
        #pragma unroll
        for (int e = 0; e < 8; ++e) cst[e] = 0.0f;

        #pragma unroll
        for (int s = 0; s < HN; ++s) {
            const int cur = s & 1;
            const int nxt = cur ^ 1;
            __syncthreads();   // staging / previous-step h writes visible

            f32x4 acc[2][4];
            #pragma unroll
            for (int mt = 0; mt < 2; ++mt)
                #pragma unroll
                for (int t = 0; t < 4; ++t)
                    acc[mt][t] = splat4(biasv[t]);

            // K-loop: 5 k-tiles, double-buffered streamed B + LDS A
            union { uint4 u; bf16x8 b; } Bb[2][4];
            bf16x8 Ab[2][2];
            #pragma unroll
            for (int t = 0; t < 4; ++t) Bb[0][t].u = Bw[t * 512];
            #pragma unroll
            for (int mt = 0; mt < 2; ++mt)
                Ab[0][mt] = *reinterpret_cast<const bf16x8*>(
                    &sA[cur * MT * ASTR + (mt * 16 + cc) * ASTR + quad * 8]);

            #pragma unroll
            for (int kt = 0; kt < 5; ++kt) {
                const int cb = kt & 1, nb = cb ^ 1;
                if (kt < 4) {
                    #pragma unroll
                    for (int t = 0; t < 4; ++t) Bb[nb][t].u = Bw[((kt + 1) * 4 + t) * 512];
                    #pragma unroll
                    for (int mt = 0; mt < 2; ++mt)
                        Ab[nb][mt] = *reinterpret_cast<const bf16x8*>(
                            &sA[cur * MT * ASTR + (mt * 16 + cc) * ASTR + (kt + 1) * 32 + quad * 8]);
                }
                #pragma unroll
                for (int t = 0; t < 4; ++t) {
                    acc[0][t] = __builtin_amdgcn_mfma_f32_16x16x32_bf16(Ab[cb][0], Bb[cb][t].b, acc[0][t], 0, 0, 0);
                    acc[1][t] = __builtin_amdgcn_mfma_f32_16x16x32_bf16(Ab[cb][1], Bb[cb][t].b, acc[1][t], 0, 0, 0);
                }
            }

            // ---- pointwise: 8 independent elements, 7 trans each ----
            // acc_i/f/o = -log2e*pre, acc_g = 2*log2e*pre (scales folded)
            const int lcol = wv * 16 + cc;
            #pragma unroll
            for (int e = 0; e < 8; ++e) {
                const int mt = e >> 2, r = e & 3;
                const float Ei = __builtin_amdgcn_exp2f(acc[mt][0][r]);   // e^-i
                const float Ef = __builtin_amdgcn_exp2f(acc[mt][1][r]);   // e^-f
                const float Eg = __builtin_amdgcn_exp2f(acc[mt][2][r]);   // e^{2g}
                const float Eo = __builtin_amdgcn_exp2f(acc[mt][3][r]);   // e^-o
                const float t1  = (1.0f + Ei) * (1.0f + Eg);
                const float ef1 = 1.0f + Ef;
                const float t3  = (Eg - 1.0f) * ef1;
                const float num = fmaf(cst[e], t1, t3);
                const float cn  = num * __builtin_amdgcn_rcpf(t1 * ef1);
                cst[e] = cn;
                const float Ec = __builtin_amdgcn_exp2f(2.0f * LOG2E * cn);  // e^{2c}
                const float hn = (Ec - 1.0f) *
                    __builtin_amdgcn_rcpf((1.0f + Eo) * (1.0f + Ec));
                const int m = mt * 16 + quad * 4 + r;
                sA[nxt * MT * ASTR + m * ASTR + 16 + lcol] = f2bf_fast(hn);
            }
        }

        __syncthreads();   // final h (buffer 1) complete

        // -------- epilogue: heads; 16 threads/row, 8 l each --------
        {
            const int row = tid >> 4;    // 0..31
            const int j   = tid & 15;    // 0..15
            const u16x8 hv8 = *reinterpret_cast<const u16x8*>(
                &sA[1 * MT * ASTR + row * ASTR + 16 + j * 8]);
            float p = 0.f, q0 = 0.f, q1 = 0.f, q2 = 0.f;
            #pragma unroll
            for (int u = 0; u < 8; ++u) {
                const int l = j * 8 + u;
                const float hv = bf2f(hv8[u]);
                p  = fmaf(hv, sWp[l], p);
                q0 = fmaf(hv, sWr[l], q0);
                q1 = fmaf(hv, sWr[128 + l], q1);
                q2 = fmaf(hv, sWr[256 + l], q2);
            }
            #pragma unroll
            for (int m = 1; m < 16; m <<= 1) {
                p  += __shfl_xor(p,  m, 64);
                q0 += __shfl_xor(q0, m, 64);
                q1 += __shfl_xor(q1, m, 64);
                q2 += __shfl_xor(q2, m, 64);
            }
            if (j == 0) {
                const int gr = r0g + row;
                const float prog  = p + bpv;
                const float rr0 = q0 + br0, rr1 = q1 + br1, rr2 = q2 + br2;
                const float rmean = (rr0 + rr1 + rr2) * (1.0f / 3.0f);
                const float s0 = sigm(rr0), s1 = sigm(rr1), s2 = sigm(rr2);
                const float sm = (s0 + s1 + s2) * (1.0f / 3.0f);
                const float d0 = s0 - sm, d1 = s1 - sm, d2 = s2 - sm;
                const float unc = (d0 * d0 + d1 * d1 + d2 * d2) * 0.5f;   // ddof=1
                out[gr]          = rmean;
                out[BK + gr]     = prog;
                out[2 * BK + gr] = unc;
                out[3 * BK + gr] = rr0;
                out[4 * BK + gr] = rr1;
                out[5 * BK + gr] = rr2;
            }
        }
        // next-tile staging writes emb/pad (both bufs) + buf0 h; epilogue reads
        // buf1 h-cols (disjoint); the step-0 barrier orders everything else.
    }
}

extern "C" void kernel_launch(void* const* d_in, const int* in_sizes, int n_in,
                              void* d_out, int out_size, void* d_ws, size_t ws_size,
                              hipStream_t stream) {
    const float* z       = (const float*)d_in[0];
    const float* anchors = (const float*)d_in[1];
    const float* W1      = (const float*)d_in[2];
    const float* b1      = (const float*)d_in[3];
    const float* W2      = (const float*)d_in[4];
    const float* b2      = (const float*)d_in[5];
    const float* Wih     = (const float*)d_in[6];
    const float* Whh     = (const float*)d_in[7];
    const float* bih     = (const float*)d_in[8];
    const float* bhh     = (const float*)d_in[9];
    const float* Wp      = (const float*)d_in[10];
    const float* bp      = (const float*)d_in[11];
    const float* Wr      = (const float*)d_in[12];
    const float* br      = (const float*)d_in[13];

    uint4* Bpk = (uint4*)d_ws;   // 10240 * 16 B = 160 KB

    hipLaunchKernelGGL(prepack_kernel, dim3(40), dim3(256), 0, stream, Wih, Whh, Bpk);
    hipLaunchKernelGGL(wahead_kernel, dim3(WGS), dim3(THREADS), 0, stream,
                       z, anchors, W1, b1, W2, b2, bih, bhh,
                       Wp, bp, Wr, br, (const uint4*)Bpk, (float*)d_out);
}

// Round 8
// 216.149 us; speedup vs baseline: 1.8731x; 1.8731x over previous
//
#include <hip/hip_runtime.h>

// Problem constants
#define BN 32768
#define KN 5
#define LN 128
#define HN 3
#define ROWS (BN*KN)        // 163840
#define BK ROWS
#define MT 64               // rows per tile
#define TILES (ROWS/MT)     // 2560
#define WGS 512
#define TPW (TILES/WGS)     // 5 tiles per workgroup
#define THREADS 512         // 8 waves
#define ASTR 168            // A row stride bf16: [emb16|h128|zero16] + 8 pad
#define LOG2E 1.44269504089f

using bf16x8 = __attribute__((ext_vector_type(8))) __bf16;
using bf16x2 = __attribute__((ext_vector_type(2))) __bf16;
using f32x4  = __attribute__((ext_vector_type(4))) float;
using u16x8  = __attribute__((ext_vector_type(8))) unsigned short;

__device__ inline unsigned short f2bf(float x) {
    union { float f; unsigned u; } v; v.f = x;
    unsigned r = v.u + 0x7FFFu + ((v.u >> 16) & 1u);   // RNE
    return (unsigned short)(r >> 16);
}
#if __has_builtin(__builtin_amdgcn_cvt_pk_bf16_f32)
__device__ inline unsigned short f2bf_fast(float x) {
    union { bf16x2 v; unsigned short us[2]; } u;
    u.v = __builtin_amdgcn_cvt_pk_bf16_f32(x, x);
    return u.us[0];
}
#else
__device__ inline unsigned short f2bf_fast(float x) { return f2bf(x); }
#endif
__device__ inline float bf2f(unsigned short b) {
    union { unsigned u; float f; } v; v.u = ((unsigned)b) << 16; return v.f;
}
__device__ inline float sigm(float x) {
    return __builtin_amdgcn_rcpf(1.0f + __builtin_amdgcn_exp2f(-LOG2E * x));
}
__device__ inline f32x4 splat4(float x) { f32x4 r; r[0]=x; r[1]=x; r[2]=x; r[3]=x; return r; }

__global__ __launch_bounds__(THREADS, 2)   // 256-reg cap: verified no-spill envelope
void wahead_kernel(const float* __restrict__ z,   const float* __restrict__ anchors,
                   const float* __restrict__ W1,  const float* __restrict__ b1,
                   const float* __restrict__ W2,  const float* __restrict__ b2,
                   const float* __restrict__ Wih, const float* __restrict__ Whh,
                   const float* __restrict__ bih, const float* __restrict__ bhh,
                   const float* __restrict__ Wp,  const float* __restrict__ bp,
                   const float* __restrict__ Wr,  const float* __restrict__ br,
                   float* __restrict__ out)
{
    __shared__ unsigned short sA[2 * MT * ASTR];   // ping-pong [emb|h|0] bf16, 43 KB
    __shared__ float sW1[32], sb1[16], sW2[16 * 17], sb2[16], sWp[128], sWr[384];

    const int tid  = threadIdx.x;
    const int wv   = tid >> 6;       // wave 0..7: owns l-cols wv*16..wv*16+15 of each gate
    const int lane = tid & 63;
    const int quad = lane >> 4;
    const int cc   = lane & 15;

    // ---- stage small constant weights into LDS ----
    if (tid < 32)  sW1[tid] = W1[tid];
    if (tid < 16)  { sb1[tid] = b1[tid]; sb2[tid] = b2[tid]; }
    if (tid < 256) sW2[(tid >> 4) * 17 + (tid & 15)] = W2[tid];   // sW2[col*17+hh]
    if (tid < 128) sWp[tid] = Wp[tid];
    if (tid < 384) sWr[tid] = Wr[tid];

    // ---- stacked-B fragments [W_ih(16)|W_hh(128)|0(16)] with FOLDED gate scales ----
    // gates i,f,o scaled by -log2e; gate g scaled by +2*log2e, so exp2() applies
    // directly to the MFMA accumulators.
    // B layout (16x16x32): n = lane&15, k = quad*8 + j
    bf16x8 Bf[4][5];
    float  biasv[4];
    #pragma unroll
    for (int t = 0; t < 4; ++t) {                      // gate i,f,g,o
        const float sc = (t == 2) ? (2.0f * LOG2E) : (-LOG2E);
        const int n = t * 128 + wv * 16 + cc;          // gate output col in [0,512)
        biasv[t] = sc * (bih[n] + bhh[n]);
        #pragma unroll
        for (int kt = 0; kt < 5; ++kt) {
            const int k0 = kt * 32 + quad * 8;
            float v[8];
            if (k0 < 16) {                             // W_ih region
                const float4 p0 = *reinterpret_cast<const float4*>(Wih + n * 16 + k0);
                const float4 p1 = *reinterpret_cast<const float4*>(Wih + n * 16 + k0 + 4);
                v[0]=p0.x; v[1]=p0.y; v[2]=p0.z; v[3]=p0.w;
                v[4]=p1.x; v[5]=p1.y; v[6]=p1.z; v[7]=p1.w;
            } else if (k0 < 144) {                     // W_hh region
                const float4 p0 = *reinterpret_cast<const float4*>(Whh + n * 128 + (k0 - 16));
                const float4 p1 = *reinterpret_cast<const float4*>(Whh + n * 128 + (k0 - 16) + 4);
                v[0]=p0.x; v[1]=p0.y; v[2]=p0.z; v[3]=p0.w;
                v[4]=p1.x; v[5]=p1.y; v[6]=p1.z; v[7]=p1.w;
            } else {                                   // zero pad k in [144,160)
                #pragma unroll
                for (int j = 0; j < 8; ++j) v[j] = 0.0f;
            }
            union { bf16x8 bv; unsigned short us[8]; } pk;
            #pragma unroll
            for (int j = 0; j < 8; ++j) pk.us[j] = f2bf(sc * v[j]);
            Bf[t][kt] = pk.bv;
        }
    }

    const float bpv = bp[0];
    const float br0 = br[0], br1 = br[1], br2 = br[2];

    __syncthreads();   // consts staged

    const int erow = tid >> 3;   // 0..63 (8 threads per row)
    const int esub = tid & 7;    // 0..7

    #pragma unroll 1
    for (int ti = 0; ti < TPW; ++ti) {
        const int tile = blockIdx.x * TPW + ti;
        const int r0g  = tile * MT;

        // -------- staging: emb MLP (2 cols/thread) + zero-pad + z --------
        {
            const int gr = r0g + erow;
            const float ax = anchors[gr * 2], ay = anchors[gr * 2 + 1];
            const int e0 = esub * 2;
            float a0 = sb2[e0], a1 = sb2[e0 + 1];
            #pragma unroll
            for (int hh = 0; hh < 16; ++hh) {
                float pre = fmaf(sW1[hh * 2], ax, fmaf(sW1[hh * 2 + 1], ay, sb1[hh]));
                pre = fmaxf(pre, 0.0f);
                a0 = fmaf(pre, sW2[e0 * 17 + hh], a0);
                a1 = fmaf(pre, sW2[(e0 + 1) * 17 + hh], a1);
            }
            const unsigned short b0 = f2bf(a0), b1v = f2bf(a1);
            #pragma unroll
            for (int bufi = 0; bufi < 2; ++bufi) {
                unsigned short* row = &sA[bufi * MT * ASTR + erow * ASTR];
                row[e0]       = b0;  row[e0 + 1]       = b1v;
                row[144 + e0] = 0;   row[144 + e0 + 1] = 0;
            }
            // initial h = z[b] (bf16) into buffer 0, cols 16..143: 16 elems/thread
            const unsigned b_idx = (unsigned)gr / 5u;
            const float4* zp = reinterpret_cast<const float4*>(z + (size_t)b_idx * 128 + esub * 16);
            const float4 z0 = zp[0], z1 = zp[1], z2 = zp[2], z3 = zp[3];
            union { u16x8 v; unsigned short us[8]; } w0, w1;
            w0.us[0]=f2bf(z0.x); w0.us[1]=f2bf(z0.y); w0.us[2]=f2bf(z0.z); w0.us[3]=f2bf(z0.w);
            w0.us[4]=f2bf(z1.x); w0.us[5]=f2bf(z1.y); w0.us[6]=f2bf(z1.z); w0.us[7]=f2bf(z1.w);
            w1.us[0]=f2bf(z2.x); w1.us[1]=f2bf(z2.y); w1.us[2]=f2bf(z2.z); w1.us[3]=f2bf(z2.w);
            w1.us[4]=f2bf(z3.x); w1.us[5]=f2bf(z3.y); w1.us[6]=f2bf(z3.z); w1.us[7]=f2bf(z3.w);
            unsigned short* hrow = &sA[erow * ASTR + 16 + esub * 16];
            *reinterpret_cast<u16x8*>(hrow)     = w0.v;
            *reinterpret_cast<u16x8*>(hrow + 8) = w1.v;
        }

        float cst[16];
        #pragma unroll
        for (int e = 0; e < 16; ++e) cst[e] = 0.0f;

        #pragma unroll
        for (int s = 0; s < HN; ++s) {
            const int cur = s & 1;
            const int nxt = cur ^ 1;
            __syncthreads();   // staging / previous-step h writes visible

            // ---- MFMA phase: all 4 m-tiles, one-mt-ahead A prefetch ----
            f32x4 acc[4][4];
            #pragma unroll
            for (int mt = 0; mt < 4; ++mt)
                #pragma unroll
                for (int t = 0; t < 4; ++t)
                    acc[mt][t] = splat4(biasv[t]);

            bf16x8 af[2][5];
            #pragma unroll
            for (int kt = 0; kt < 5; ++kt)
                af[0][kt] = *reinterpret_cast<const bf16x8*>(
                    &sA[cur * MT * ASTR + cc * ASTR + kt * 32 + quad * 8]);
            #pragma unroll
            for (int mt = 0; mt < 4; ++mt) {
                const int pb = mt & 1;
                if (mt < 3) {
                    #pragma unroll
                    for (int kt = 0; kt < 5; ++kt)
                        af[pb ^ 1][kt] = *reinterpret_cast<const bf16x8*>(
                            &sA[cur * MT * ASTR + ((mt + 1) * 16 + cc) * ASTR + kt * 32 + quad * 8]);
                }
                #pragma unroll
                for (int kt = 0; kt < 5; ++kt)
                    #pragma unroll
                    for (int t = 0; t < 4; ++t)
                        acc[mt][t] = __builtin_amdgcn_mfma_f32_16x16x32_bf16(
                            af[pb][kt], Bf[t][kt], acc[mt][t], 0, 0, 0);
            }

            // ---- pointwise phase: 4 groups of 4 (group = m-tile), batched rcp ----
            // acc_i/f/o = -log2e*pre, acc_g = 2*log2e*pre (scales folded into B)
            const int lcol = wv * 16 + cc;
            #pragma unroll
            for (int mt = 0; mt < 4; ++mt) {
                float Eg[4], Eo[4], num[4], den[4];
                // gate exponentials + first denominator, 4-wide
                #pragma unroll
                for (int r = 0; r < 4; ++r) {
                    const float Ei = __builtin_amdgcn_exp2f(acc[mt][0][r]);   // e^-i
                    const float Ef = __builtin_amdgcn_exp2f(acc[mt][1][r]);   // e^-f
                    Eg[r] = __builtin_amdgcn_exp2f(acc[mt][2][r]);            // e^{2g}
                    Eo[r] = __builtin_amdgcn_exp2f(acc[mt][3][r]);            // e^-o
                    const float t1  = (1.0f + Ei) * (1.0f + Eg[r]);
                    const float ef1 = 1.0f + Ef;
                    num[r] = fmaf(cst[mt * 4 + r], t1, (Eg[r] - 1.0f) * ef1);
                    den[r] = t1 * ef1;
                }
                // batched reciprocal #1: 4 dens -> 1 v_rcp
                {
                    const float p01  = den[0] * den[1];
                    const float p012 = p01 * den[2];
                    const float R    = __builtin_amdgcn_rcpf(p012 * den[3]);
                    const float inv3 = R * p012;
                    const float R3   = R * den[3];
                    const float inv2 = R3 * p01;
                    const float R23  = R3 * den[2];
                    num[0] *= R23 * den[1];
                    num[1] *= R23 * den[0];
                    num[2] *= inv2;
                    num[3] *= inv3;
                }
                float Ec[4];
                #pragma unroll
                for (int r = 0; r < 4; ++r) {
                    cst[mt * 4 + r] = num[r];                                  // c'
                    Ec[r] = __builtin_amdgcn_exp2f(2.0f * LOG2E * num[r]);     // e^{2c}
                    den[r] = (1.0f + Eo[r]) * (1.0f + Ec[r]);
                }
                // batched reciprocal #2
                {
                    const float p01  = den[0] * den[1];
                    const float p012 = p01 * den[2];
                    const float R    = __builtin_amdgcn_rcpf(p012 * den[3]);
                    const float inv3 = R * p012;
                    const float R3   = R * den[3];
                    const float inv2 = R3 * p01;
                    const float R23  = R3 * den[2];
                    den[0] = R23 * den[1];
                    den[1] = R23 * den[0 + 0];   // careful: need original den[0]
                    // NOTE: den[0] was just overwritten; recompute via saved values below
                    den[1] = inv2;               // placeholder fixed below
                    den[2] = inv2;
                    den[3] = inv3;
                }
                // The above in-place aliasing is error-prone; do it cleanly:
                // (recompute batched inverse with distinct outputs)
                // -- replaced by the block below --
                #pragma unroll
                for (int r = 0; r < 4; ++r) {
                    // den[] now holds garbage for r<3 from the aliasing above;
                    // recompute exact inverses cheaply and correctly:
                    den[r] = (1.0f + Eo[r]) * (1.0f + Ec[r]);
                }
                {
                    const float p01  = den[0] * den[1];
                    const float p012 = p01 * den[2];
                    const float R    = __builtin_amdgcn_rcpf(p012 * den[3]);
                    const float inv3 = R * p012;
                    const float R3   = R * den[3];
                    const float inv2 = R3 * p01;
                    const float R23  = R3 * den[2];
                    const float inv1 = R23 * den[0];
                    const float inv0 = R23 * den[1];
                    const int m0 = mt * 16 + quad * 4;
                    sA[nxt * MT * ASTR + (m0 + 0) * ASTR + 16 + lcol] =
                        f2bf_fast((Ec[0] - 1.0f) * inv0);
                    sA[nxt * MT * ASTR + (m0 + 1) * ASTR + 16 + lcol] =
                        f2bf_fast((Ec[1] - 1.0f) * inv1);
                    sA[nxt * MT * ASTR + (m0 + 2) * ASTR + 16 + lcol] =
                        f2bf_fast((Ec[2] - 1.0f) * inv2);
                    sA[nxt * MT * ASTR + (m0 + 3) * ASTR + 16 + lcol] =
                        f2bf_fast((Ec[3] - 1.0f) * inv3);
                }
            }
        }

        __syncthreads();   // final h (buffer 1) complete

        // -------- epilogue: heads; 8 threads/row, 16 l each --------
        {
            const int row = tid >> 3;    // 0..63
            const int j   = tid & 7;     // 0..7
            const unsigned short* hrow = &sA[1 * MT * ASTR + row * ASTR + 16 + j * 16];
            const u16x8 h0 = *reinterpret_cast<const u16x8*>(hrow);
            const u16x8 h1 = *reinterpret_cast<const u16x8*>(hrow + 8);
            float p = 0.f, q0 = 0.f, q1 = 0.f, q2 = 0.f;
            #pragma unroll
            for (int u = 0; u < 16; ++u) {
                const int l = j * 16 + u;
                const float hv = bf2f(u < 8 ? h0[u] : h1[u - 8]);
                p  = fmaf(hv, sWp[l], p);
                q0 = fmaf(hv, sWr[l], q0);
                q1 = fmaf(hv, sWr[128 + l], q1);
                q2 = fmaf(hv, sWr[256 + l], q2);
            }
            #pragma unroll
            for (int m = 1; m < 8; m <<= 1) {
                p  += __shfl_xor(p,  m, 64);
                q0 += __shfl_xor(q0, m, 64);
                q1 += __shfl_xor(q1, m, 64);
                q2 += __shfl_xor(q2, m, 64);
            }
            if (j == 0) {
                const int gr = r0g + row;
                const float prog  = p + bpv;
                const float rr0 = q0 + br0, rr1 = q1 + br1, rr2 = q2 + br2;
                const float rmean = (rr0 + rr1 + rr2) * (1.0f / 3.0f);
                const float s0 = sigm(rr0), s1 = sigm(rr1), s2 = sigm(rr2);
                const float sm = (s0 + s1 + s2) * (1.0f / 3.0f);
                const float d0 = s0 - sm, d1 = s1 - sm, d2 = s2 - sm;
                const float unc = (d0 * d0 + d1 * d1 + d2 * d2) * 0.5f;   // ddof=1
                out[gr]          = rmean;
                out[BK + gr]     = prog;
                out[2 * BK + gr] = unc;
                out[3 * BK + gr] = rr0;
                out[4 * BK + gr] = rr1;
                out[5 * BK + gr] = rr2;
            }
        }
        // next-tile staging writes emb/pad (both bufs) + buf0 h; epilogue reads
        // buf1 h-cols (disjoint); the step-0 barrier orders everything else.
    }
}

extern "C" void kernel_launch(void* const* d_in, const int* in_sizes, int n_in,
                              void* d_out, int out_size, void* d_ws, size_t ws_size,
                              hipStream_t stream) {
    const float* z       = (const float*)d_in[0];
    const float* anchors = (const float*)d_in[1];
    const float* W1      = (const float*)d_in[2];
    const float* b1      = (const float*)d_in[3];
    const float* W2      = (const float*)d_in[4];
    const float* b2      = (const float*)d_in[5];
    const float* Wih     = (const float*)d_in[6];
    const float* Whh     = (const float*)d_in[7];
    const float* bih     = (const float*)d_in[8];
    const float* bhh     = (const float*)d_in[9];
    const float* Wp      = (const float*)d_in[10];
    const float* bp      = (const float*)d_in[11];
    const float* Wr      = (const float*)d_in[12];
    const float* br      = (const float*)d_in[13];

    hipLaunchKernelGGL(wahead_kernel, dim3(WGS), dim3(THREADS), 0, stream,
                       z, anchors, W1, b1, W2, b2, Wih, Whh, bih, bhh,
                       Wp, bp, Wr, br, (float*)d_out);
}